// Round 5
// baseline (243.422 us; speedup 1.0000x reference)
//
#include <hip/hip_runtime.h>
#include <hip/hip_bf16.h>

typedef __bf16 bf16x8 __attribute__((ext_vector_type(8)));
typedef float f32x4 __attribute__((ext_vector_type(4)));
typedef float f32x16 __attribute__((ext_vector_type(16)));

#define B_N 2048
#define O_N 2048
#define K_N 64

__device__ __forceinline__ void gld16(const void* g, void* l) {
    __builtin_amdgcn_global_load_lds(
        (const __attribute__((address_space(1))) void*)g,
        (__attribute__((address_space(3))) void*)l,
        16, 0, 0);
}

// ---------------------------------------------------------------------------
// prep (unchanged from R4):
//   Atp[o]: A-op panel, element(ss,j,h,e) at ss*1024 + j*16 + h*8 + e
//           = bf16( inv[o][16ss+8h+e][j]^2 )          (8KB per o)
//   cPhi/cPlo: c = -(A^T+A)m in bf16 hi/lo, MFMA-A-frag layout (32-o groups)
//   kArr[o] = m^T A m (f32)
// ---------------------------------------------------------------------------
__global__ __launch_bounds__(256) void rbf_prep(
    const float* __restrict__ inv, const float* __restrict__ means,
    __bf16* __restrict__ Atp, __bf16* __restrict__ cPhi,
    __bf16* __restrict__ cPlo, float* __restrict__ kArr)
{
    __shared__ float s[64 * 65];
    __shared__ float mld[64];
    __shared__ float uw[128];
    const int o = blockIdx.x;
    const int t = threadIdx.x;
    const float4* src = (const float4*)(inv + (size_t)o * 4096);
#pragma unroll
    for (int k = 0; k < 4; ++k) {
        const int idx = k * 256 + t;
        const float4 v = src[idx];
        const int i = idx >> 4;
        const int j0 = (idx & 15) * 4;
        s[i * 65 + j0 + 0] = v.x * v.x;
        s[i * 65 + j0 + 1] = v.y * v.y;
        s[i * 65 + j0 + 2] = v.z * v.z;
        s[i * 65 + j0 + 3] = v.w * v.w;
    }
    if (t < 64) mld[t] = means[(size_t)t * O_N + o];
    __syncthreads();
    if (t < 64) {
        float u = 0.f;
#pragma unroll
        for (int i = 0; i < 64; ++i) u = fmaf(s[i * 65 + t], mld[i], u);
        uw[t] = u;
    } else if (t < 128) {
        const int j = t - 64;
        float w = 0.f;
#pragma unroll
        for (int i = 0; i < 64; ++i) w = fmaf(s[j * 65 + i], mld[i], w);
        uw[64 + j] = w;
    }
    __syncthreads();
    if (t < 64) {
        const float c = -(uw[t] + uw[64 + t]);
        const __bf16 hi = (__bf16)c;
        const __bf16 lo = (__bf16)(c - (float)hi);
        const size_t eidx = (size_t)(o >> 5) * 2048 + (size_t)(t >> 4) * 512
                          + (size_t)(o & 31) * 16 + (t & 15);
        cPhi[eidx] = hi;
        cPlo[eidx] = lo;
    }
    if (t == 0) {
        float kk = 0.f;
#pragma unroll
        for (int j = 0; j < 64; ++j) kk = fmaf(uw[j], mld[j], kk);
        kArr[o] = kk;
    }
#pragma unroll
    for (int r = 0; r < 2; ++r) {
        const int ch = r * 256 + t;
        const int ss = ch >> 7;
        const int j = (ch >> 1) & 63;
        const int hh = ch & 1;
        bf16x8 v;
#pragma unroll
        for (int e = 0; e < 8; ++e)
            v[e] = (__bf16)s[(16 * ss + 8 * hh + e) * 65 + j];
        *(bf16x8*)(Atp + (size_t)o * 4096 + (size_t)ch * 8) = v;
    }
}

// ---------------------------------------------------------------------------
// main: block = 256 rows x 16 o's; 4 waves x 64 rows (2 row-tiles of 32).
// Grid 1024 -> 4 blocks/CU (LDS ~33KB), 16 waves/CU, 4 waves/SIMD feeding
// the matrix pipe. Simple 2-buffer + __syncthreads staging (1 barrier/iter).
// C-layout (32x32): col = lane&31, row = (reg&3)+8*(reg>>2)+4*(lane>>5).
// ---------------------------------------------------------------------------
__global__ __launch_bounds__(256, 4) void rbf_main(
    const float* __restrict__ x, const __bf16* __restrict__ Atp,
    const __bf16* __restrict__ cPhi, const __bf16* __restrict__ cPlo,
    const float* __restrict__ kArr, float* __restrict__ out)
{
    __shared__ __align__(16) __bf16 sA[2][4096];
    __shared__ __align__(16) float sLin[4][16][64];
    __shared__ float sK[16];

    const int tid = threadIdx.x;
    const int wave = tid >> 6;
    const int lane = tid & 63;
    const int b = lane & 31;
    const int h = lane >> 5;

    // 1024 blocks = 8 XCD x (16 og x 8 bg); per-XCD Atp slice = 256 o = 2MB
    const int wg = (int)blockIdx.x;
    const int xcd = wg & 7;
    const int loc = wg >> 3;               // 0..127
    const int og = xcd * 16 + (loc >> 3);  // 0..127 (16-o groups)
    const int bg = loc & 7;                // 0..7
    const int oBase = og * 16;
    const int rowW = bg * 256 + wave * 64;

    const float* xr0 = x + (size_t)(rowW + b) * K_N;
    const float* xr1 = x + (size_t)(rowW + 32 + b) * K_N;

    const f32x16 zz = {0.f,0.f,0.f,0.f,0.f,0.f,0.f,0.f,
                       0.f,0.f,0.f,0.f,0.f,0.f,0.f,0.f};

    // x bf16 B-op frags (both tiles) + f32 dot copies
    bf16x8 xh[2][4];
    f32x4 xd[2][2][4];
    {
        bf16x8 xl[2][4];
#pragma unroll
        for (int t = 0; t < 2; ++t) {
            const float* xr = t ? xr1 : xr0;
#pragma unroll
            for (int ss = 0; ss < 4; ++ss) {
                const float* p = xr + ss * 16 + h * 8;
                bf16x8 vh, vl;
#pragma unroll
                for (int e = 0; e < 8; ++e) {
                    const float v = p[e];
                    const __bf16 hi = (__bf16)v;
                    vh[e] = hi;
                    vl[e] = (__bf16)(v - (float)hi);
                }
                xh[t][ss] = vh; xl[t][ss] = vl;
            }
#pragma unroll
            for (int mt = 0; mt < 2; ++mt)
#pragma unroll
                for (int rq = 0; rq < 4; ++rq)
                    xd[t][mt][rq] = *(const f32x4*)(xr + mt * 32 + rq * 8 + h * 4);
        }
        // linear-term GEMM (32 o x 64 rows); keep this block's 16-o half.
        const int og32 = og >> 1;
        const int sel = og & 1;
        const __bf16* chp = cPhi + (size_t)og32 * 2048;
        const __bf16* clp = cPlo + (size_t)og32 * 2048;
        bf16x8 fh[4], fl[4];
#pragma unroll
        for (int ss = 0; ss < 4; ++ss) {
            fh[ss] = *(const bf16x8*)(chp + ss * 512 + b * 16 + h * 8);
            fl[ss] = *(const bf16x8*)(clp + ss * 512 + b * 16 + h * 8);
        }
#pragma unroll
        for (int t = 0; t < 2; ++t) {
            f32x16 lin = zz;
#pragma unroll
            for (int ss = 0; ss < 4; ++ss) {
                lin = __builtin_amdgcn_mfma_f32_32x32x16_bf16(fh[ss], xh[t][ss], lin, 0, 0, 0);
                lin = __builtin_amdgcn_mfma_f32_32x32x16_bf16(fh[ss], xl[t][ss], lin, 0, 0, 0);
                lin = __builtin_amdgcn_mfma_f32_32x32x16_bf16(fl[ss], xh[t][ss], lin, 0, 0, 0);
            }
            if (sel == 0) {
#pragma unroll
                for (int r = 0; r < 8; ++r)
                    sLin[wave][(r & 3) + 8 * (r >> 2) + 4 * h][t * 32 + b] = lin[r];
            } else {
#pragma unroll
                for (int r = 8; r < 16; ++r)
                    sLin[wave][(r & 3) + 8 * (r >> 2) + 4 * h - 16][t * 32 + b] = lin[r];
            }
        }
    }
    if (tid < 16) sK[tid] = kArr[oBase + tid];

    // staging: linear LDS dest, pre-swizzled global src (involution swz)
    const int L0 = tid * 16, L1 = 4096 + tid * 16;
    const int S0 = L0 ^ (((L0 >> 7) & 7) << 4);
    const int S1 = L1 ^ (((L1 >> 7) & 7) << 4);
    const char* gp = (const char*)(Atp + (size_t)oBase * 4096);
    gld16(gp + S0, (char*)&sA[0][0] + L0);
    gld16(gp + S1, (char*)&sA[0][0] + L1);

    const int off0 = (b * 32 + h * 16) ^ (((b >> 2) & 7) << 4);
    float* outp = out + (size_t)(rowW + lane) * O_N + oBase;

    float q4[4];
#pragma unroll 4
    for (int i = 0; i < 16; ++i) {
        __syncthreads();   // drains stage of buf[i&1]; frees buf[(i+1)&1]
        if (i < 15) {
            const char* gn = gp + (size_t)(i + 1) * 8192;
            char* ld = (char*)&sA[(i + 1) & 1][0];
            gld16(gn + S0, ld + L0);
            gld16(gn + S1, ld + L1);
        }
        const char* bufp = (const char*)&sA[i & 1][0];

        __builtin_amdgcn_s_setprio(1);
        f32x16 a00 = zz, a01 = zz, a10 = zz, a11 = zz;
#pragma unroll
        for (int ss = 0; ss < 4; ++ss) {
            const char* base = bufp + ss * 2048;
            const bf16x8 f0 = *(const bf16x8*)(base + off0);
            const bf16x8 f1 = *(const bf16x8*)(base + 1024 + off0);
            a00 = __builtin_amdgcn_mfma_f32_32x32x16_bf16(f0, xh[0][ss], a00, 0, 0, 0);
            a10 = __builtin_amdgcn_mfma_f32_32x32x16_bf16(f0, xh[1][ss], a10, 0, 0, 0);
            a01 = __builtin_amdgcn_mfma_f32_32x32x16_bf16(f1, xh[0][ss], a01, 0, 0, 0);
            a11 = __builtin_amdgcn_mfma_f32_32x32x16_bf16(f1, xh[1][ss], a11, 0, 0, 0);
        }
        __builtin_amdgcn_s_setprio(0);

        const float kk = sK[i];
        float ev0, ev1;
        {   // tile 0
            float p0 = 0.f, p1 = 0.f, p2 = 0.f, p3 = 0.f;
#pragma unroll
            for (int e = 0; e < 4; ++e) {
                p0 = fmaf(a00[e],      xd[0][0][0][e], p0);
                p1 = fmaf(a00[4 + e],  xd[0][0][1][e], p1);
                p2 = fmaf(a00[8 + e],  xd[0][0][2][e], p2);
                p3 = fmaf(a00[12 + e], xd[0][0][3][e], p3);
                p0 = fmaf(a01[e],      xd[0][1][0][e], p0);
                p1 = fmaf(a01[4 + e],  xd[0][1][1][e], p1);
                p2 = fmaf(a01[8 + e],  xd[0][1][2][e], p2);
                p3 = fmaf(a01[12 + e], xd[0][1][3][e], p3);
            }
            float q = (p0 + p1) + (p2 + p3);
            q += __shfl_xor(q, 32, 64);
            q += sLin[wave][i][b] + kk;
            ev0 = exp2f(q * -0.72134752044448170368f);
        }
        {   // tile 1
            float p0 = 0.f, p1 = 0.f, p2 = 0.f, p3 = 0.f;
#pragma unroll
            for (int e = 0; e < 4; ++e) {
                p0 = fmaf(a10[e],      xd[1][0][0][e], p0);
                p1 = fmaf(a10[4 + e],  xd[1][0][1][e], p1);
                p2 = fmaf(a10[8 + e],  xd[1][0][2][e], p2);
                p3 = fmaf(a10[12 + e], xd[1][0][3][e], p3);
                p0 = fmaf(a11[e],      xd[1][1][0][e], p0);
                p1 = fmaf(a11[4 + e],  xd[1][1][1][e], p1);
                p2 = fmaf(a11[8 + e],  xd[1][1][2][e], p2);
                p3 = fmaf(a11[12 + e], xd[1][1][3][e], p3);
            }
            float q = (p0 + p1) + (p2 + p3);
            q += __shfl_xor(q, 32, 64);
            q += sLin[wave][i][32 + b] + kk;
            ev1 = exp2f(q * -0.72134752044448170368f);
        }
        q4[i & 3] = h ? ev1 : ev0;   // this thread's own row = rowW + lane

        if ((i & 3) == 3) {
            const f32x4 v = {q4[0], q4[1], q4[2], q4[3]};
            *(f32x4*)(outp + (i - 3)) = v;
        }
    }
}

extern "C" void kernel_launch(void* const* d_in, const int* in_sizes, int n_in,
                              void* d_out, int out_size, void* d_ws, size_t ws_size,
                              hipStream_t stream)
{
    const float* x = (const float*)d_in[0];
    const float* means = (const float*)d_in[1];
    const float* inv = (const float*)d_in[2];
    float* out = (float*)d_out;

    char* w = (char*)d_ws;
    __bf16* Atp  = (__bf16*)w;                                     // 16.78 MB
    __bf16* cPhi = (__bf16*)(w + (size_t)O_N * 4096 * 2);          // 256 KB
    __bf16* cPlo = (__bf16*)(w + (size_t)O_N * 4096 * 2 + 262144); // 256 KB
    float*  kArr = (float*)(w + (size_t)O_N * 4096 * 2 + 524288);  // 8 KB

    rbf_prep<<<dim3(O_N), dim3(256), 0, stream>>>(inv, means, Atp, cPhi, cPlo, kArr);
    rbf_main<<<dim3(1024), dim3(256), 0, stream>>>(x, Atp, cPhi, cPlo, kArr, out);

    (void)in_sizes; (void)n_in; (void)out_size; (void)ws_size;
}

// Round 6
// 63.649 us; speedup vs baseline: 3.8244x; 3.8244x over previous
//
#include <hip/hip_runtime.h>
#include <hip/hip_bf16.h>

typedef __bf16 bf16x8 __attribute__((ext_vector_type(8)));
typedef float f32x4 __attribute__((ext_vector_type(4)));
typedef float f32x16 __attribute__((ext_vector_type(16)));

#define B_N 2048
#define O_N 2048
#define K_N 64

__device__ __forceinline__ void gld16(const void* g, void* l) {
    __builtin_amdgcn_global_load_lds(
        (const __attribute__((address_space(1))) void*)g,
        (__attribute__((address_space(3))) void*)l,
        16, 0, 0);
}

// ---------------------------------------------------------------------------
// prep (unchanged):
//   Atp[o]: A-op panel, element(ss,j,h,e) at ss*1024 + j*16 + h*8 + e
//           = bf16( inv[o][16ss+8h+e][j]^2 )          (8KB per o)
//   cPhi/cPlo: c = -(A^T+A)m in bf16 hi/lo, MFMA-A-frag layout (32-o groups)
//   kArr[o] = m^T A m (f32)
// ---------------------------------------------------------------------------
__global__ __launch_bounds__(256) void rbf_prep(
    const float* __restrict__ inv, const float* __restrict__ means,
    __bf16* __restrict__ Atp, __bf16* __restrict__ cPhi,
    __bf16* __restrict__ cPlo, float* __restrict__ kArr)
{
    __shared__ float s[64 * 65];
    __shared__ float mld[64];
    __shared__ float uw[128];
    const int o = blockIdx.x;
    const int t = threadIdx.x;
    const float4* src = (const float4*)(inv + (size_t)o * 4096);
#pragma unroll
    for (int k = 0; k < 4; ++k) {
        const int idx = k * 256 + t;
        const float4 v = src[idx];
        const int i = idx >> 4;
        const int j0 = (idx & 15) * 4;
        s[i * 65 + j0 + 0] = v.x * v.x;
        s[i * 65 + j0 + 1] = v.y * v.y;
        s[i * 65 + j0 + 2] = v.z * v.z;
        s[i * 65 + j0 + 3] = v.w * v.w;
    }
    if (t < 64) mld[t] = means[(size_t)t * O_N + o];
    __syncthreads();
    if (t < 64) {
        float u = 0.f;
#pragma unroll
        for (int i = 0; i < 64; ++i) u = fmaf(s[i * 65 + t], mld[i], u);
        uw[t] = u;
    } else if (t < 128) {
        const int j = t - 64;
        float w = 0.f;
#pragma unroll
        for (int i = 0; i < 64; ++i) w = fmaf(s[j * 65 + i], mld[i], w);
        uw[64 + j] = w;
    }
    __syncthreads();
    if (t < 64) {
        const float c = -(uw[t] + uw[64 + t]);
        const __bf16 hi = (__bf16)c;
        const __bf16 lo = (__bf16)(c - (float)hi);
        const size_t eidx = (size_t)(o >> 5) * 2048 + (size_t)(t >> 4) * 512
                          + (size_t)(o & 31) * 16 + (t & 15);
        cPhi[eidx] = hi;
        cPlo[eidx] = lo;
    }
    if (t == 0) {
        float kk = 0.f;
#pragma unroll
        for (int j = 0; j < 64; ++j) kk = fmaf(uw[j], mld[j], kk);
        kArr[o] = kk;
    }
#pragma unroll
    for (int r = 0; r < 2; ++r) {
        const int ch = r * 256 + t;
        const int ss = ch >> 7;
        const int j = (ch >> 1) & 63;
        const int hh = ch & 1;
        bf16x8 v;
#pragma unroll
        for (int e = 0; e < 8; ++e)
            v[e] = (__bf16)s[(16 * ss + 8 * hh + e) * 65 + j];
        *(bf16x8*)(Atp + (size_t)o * 4096 + (size_t)ch * 8) = v;
    }
}

// ---------------------------------------------------------------------------
// main: block = 128 rows x 32 o's; 4 waves x 1 row-tile of 32 rows.
// Grid 1024 = 8 XCD x 8 og x 16 bg -> 4 blocks/CU (LDS 33KB), 16 waves/CU,
// 4 independent barrier groups per SIMD hide each other's tails/barriers.
// Output: each block writes FULL 128B lines (32 o) - no cross-block line
// sharing (R5's 16-o half-line writes caused 668MB L2 thrash).
// C-layout (32x32): col = lane&31, row = (reg&3)+8*(reg>>2)+4*(lane>>5).
// ---------------------------------------------------------------------------
__global__ __launch_bounds__(256, 4) void rbf_main(
    const float* __restrict__ x, const __bf16* __restrict__ Atp,
    const __bf16* __restrict__ cPhi, const __bf16* __restrict__ cPlo,
    const float* __restrict__ kArr, float* __restrict__ out)
{
    __shared__ __align__(16) __bf16 sA[2][4096];
    __shared__ __align__(16) float sLin[4][32][32];
    __shared__ float sK[32];

    const int tid = threadIdx.x;
    const int wave = tid >> 6;
    const int lane = tid & 63;
    const int b = lane & 31;
    const int h = lane >> 5;

    // 1024 blocks = 8 XCD x (8 og x 16 bg); per-XCD Atp slice = 256 o = 2MB
    const int wg = (int)blockIdx.x;
    const int xcd = wg & 7;
    const int loc = wg >> 3;               // 0..127
    const int og = xcd * 8 + (loc >> 4);   // 0..63 (32-o groups)
    const int bg = loc & 15;               // 0..15
    const int oBase = og * 32;
    const int rowW = bg * 128 + wave * 32;

    const float* xr = x + (size_t)(rowW + b) * K_N;

    const f32x16 zz = {0.f,0.f,0.f,0.f,0.f,0.f,0.f,0.f,
                       0.f,0.f,0.f,0.f,0.f,0.f,0.f,0.f};

    // x bf16 B-op frags + f32 dot copies (single 32-row tile)
    bf16x8 xh[4];
    f32x4 xd[2][4];
    {
        bf16x8 xl[4];
#pragma unroll
        for (int ss = 0; ss < 4; ++ss) {
            const float* p = xr + ss * 16 + h * 8;
            bf16x8 vh, vl;
#pragma unroll
            for (int e = 0; e < 8; ++e) {
                const float v = p[e];
                const __bf16 hi = (__bf16)v;
                vh[e] = hi;
                vl[e] = (__bf16)(v - (float)hi);
            }
            xh[ss] = vh; xl[ss] = vl;
        }
#pragma unroll
        for (int mt = 0; mt < 2; ++mt)
#pragma unroll
            for (int rq = 0; rq < 4; ++rq)
                xd[mt][rq] = *(const f32x4*)(xr + mt * 32 + rq * 8 + h * 4);

        // linear-term GEMM: lin[o][row] for this wave's 32 rows
        const __bf16* chp = cPhi + (size_t)og * 2048;
        const __bf16* clp = cPlo + (size_t)og * 2048;
        f32x16 lin = zz;
#pragma unroll
        for (int ss = 0; ss < 4; ++ss) {
            const bf16x8 fh = *(const bf16x8*)(chp + ss * 512 + b * 16 + h * 8);
            const bf16x8 fl = *(const bf16x8*)(clp + ss * 512 + b * 16 + h * 8);
            lin = __builtin_amdgcn_mfma_f32_32x32x16_bf16(fh, xh[ss], lin, 0, 0, 0);
            lin = __builtin_amdgcn_mfma_f32_32x32x16_bf16(fh, xl[ss], lin, 0, 0, 0);
            lin = __builtin_amdgcn_mfma_f32_32x32x16_bf16(fl, xh[ss], lin, 0, 0, 0);
        }
#pragma unroll
        for (int r = 0; r < 16; ++r)
            sLin[wave][(r & 3) + 8 * (r >> 2) + 4 * h][b] = lin[r];
    }
    if (tid < 32) sK[tid] = kArr[oBase + tid];

    // staging: linear LDS dest, pre-swizzled global src (involution swz)
    const int L0 = tid * 16, L1 = 4096 + tid * 16;
    const int S0 = L0 ^ (((L0 >> 7) & 7) << 4);
    const int S1 = L1 ^ (((L1 >> 7) & 7) << 4);
    const char* gp = (const char*)(Atp + (size_t)oBase * 4096);
    gld16(gp + S0, (char*)&sA[0][0] + L0);
    gld16(gp + S1, (char*)&sA[0][0] + L1);

    const int off0 = (b * 32 + h * 16) ^ (((b >> 2) & 7) << 4);
    float* outp = out + (size_t)(rowW + b) * O_N + oBase;

    float q4[4];
#pragma unroll 4
    for (int i = 0; i < 32; ++i) {
        __syncthreads();   // stage of buf[i&1] done; buf[(i+1)&1] free
        if (i < 31) {
            const char* gn = gp + (size_t)(i + 1) * 8192;
            char* ld = (char*)&sA[(i + 1) & 1][0];
            gld16(gn + S0, ld + L0);
            gld16(gn + S1, ld + L1);
        }
        const char* bufp = (const char*)&sA[i & 1][0];

        __builtin_amdgcn_s_setprio(1);
        f32x16 a0 = zz, a1 = zz;
#pragma unroll
        for (int ss = 0; ss < 4; ++ss) {
            const char* base = bufp + ss * 2048;
            const bf16x8 f0 = *(const bf16x8*)(base + off0);
            const bf16x8 f1 = *(const bf16x8*)(base + 1024 + off0);
            a0 = __builtin_amdgcn_mfma_f32_32x32x16_bf16(f0, xh[ss], a0, 0, 0, 0);
            a1 = __builtin_amdgcn_mfma_f32_32x32x16_bf16(f1, xh[ss], a1, 0, 0, 0);
        }
        __builtin_amdgcn_s_setprio(0);

        // dot: q = sum_j Y[j][row] * x[row][j]  (16 j's per h-half)
        float p0 = 0.f, p1 = 0.f, p2 = 0.f, p3 = 0.f;
#pragma unroll
        for (int e = 0; e < 4; ++e) {
            p0 = fmaf(a0[e],      xd[0][0][e], p0);
            p1 = fmaf(a0[4 + e],  xd[0][1][e], p1);
            p2 = fmaf(a0[8 + e],  xd[0][2][e], p2);
            p3 = fmaf(a0[12 + e], xd[0][3][e], p3);
            p0 = fmaf(a1[e],      xd[1][0][e], p0);
            p1 = fmaf(a1[4 + e],  xd[1][1][e], p1);
            p2 = fmaf(a1[8 + e],  xd[1][2][e], p2);
            p3 = fmaf(a1[12 + e], xd[1][3][e], p3);
        }
        float q = (p0 + p1) + (p2 + p3);
        q += __shfl_xor(q, 32, 64);          // combine h-halves (j sets)
        q += sLin[wave][i][b] + sK[i];
        q4[i & 3] = exp2f(q * -0.72134752044448170368f);

        // h-halves alternate store quads (both hold identical q4)
        if ((i & 3) == 3 && h == ((i >> 2) & 1)) {
            const f32x4 v = {q4[0], q4[1], q4[2], q4[3]};
            *(f32x4*)(outp + (i - 3)) = v;
        }
    }
}

extern "C" void kernel_launch(void* const* d_in, const int* in_sizes, int n_in,
                              void* d_out, int out_size, void* d_ws, size_t ws_size,
                              hipStream_t stream)
{
    const float* x = (const float*)d_in[0];
    const float* means = (const float*)d_in[1];
    const float* inv = (const float*)d_in[2];
    float* out = (float*)d_out;

    char* w = (char*)d_ws;
    __bf16* Atp  = (__bf16*)w;                                     // 16.78 MB
    __bf16* cPhi = (__bf16*)(w + (size_t)O_N * 4096 * 2);          // 256 KB
    __bf16* cPlo = (__bf16*)(w + (size_t)O_N * 4096 * 2 + 262144); // 256 KB
    float*  kArr = (float*)(w + (size_t)O_N * 4096 * 2 + 524288);  // 8 KB

    rbf_prep<<<dim3(O_N), dim3(256), 0, stream>>>(inv, means, Atp, cPhi, cPlo, kArr);
    rbf_main<<<dim3(1024), dim3(256), 0, stream>>>(x, Atp, cPhi, cPlo, kArr, out);

    (void)in_sizes; (void)n_in; (void)out_size; (void)ws_size;
}

// Round 7
// 60.651 us; speedup vs baseline: 4.0135x; 1.0494x over previous
//
#include <hip/hip_runtime.h>
#include <hip/hip_bf16.h>

typedef __bf16 bf16x8 __attribute__((ext_vector_type(8)));
typedef float f32x2 __attribute__((ext_vector_type(2)));
typedef float f32x4 __attribute__((ext_vector_type(4)));
typedef float f32x16 __attribute__((ext_vector_type(16)));

#define B_N 2048
#define O_N 2048
#define K_N 64

__device__ __forceinline__ void gld16(const void* g, void* l) {
    __builtin_amdgcn_global_load_lds(
        (const __attribute__((address_space(1))) void*)g,
        (__attribute__((address_space(3))) void*)l,
        16, 0, 0);
}

// ---------------------------------------------------------------------------
// prep (unchanged):
//   Atp[o]: A-op panel, element(ss,j,h,e) at ss*1024 + j*16 + h*8 + e
//           = bf16( inv[o][16ss+8h+e][j]^2 )          (8KB per o)
//   cPhi/cPlo: c = -(A^T+A)m in bf16 hi/lo, MFMA-A-frag layout (32-o groups)
//   kArr[o] = m^T A m (f32)
// ---------------------------------------------------------------------------
__global__ __launch_bounds__(256) void rbf_prep(
    const float* __restrict__ inv, const float* __restrict__ means,
    __bf16* __restrict__ Atp, __bf16* __restrict__ cPhi,
    __bf16* __restrict__ cPlo, float* __restrict__ kArr)
{
    __shared__ float s[64 * 65];
    __shared__ float mld[64];
    __shared__ float uw[128];
    const int o = blockIdx.x;
    const int t = threadIdx.x;
    const float4* src = (const float4*)(inv + (size_t)o * 4096);
#pragma unroll
    for (int k = 0; k < 4; ++k) {
        const int idx = k * 256 + t;
        const float4 v = src[idx];
        const int i = idx >> 4;
        const int j0 = (idx & 15) * 4;
        s[i * 65 + j0 + 0] = v.x * v.x;
        s[i * 65 + j0 + 1] = v.y * v.y;
        s[i * 65 + j0 + 2] = v.z * v.z;
        s[i * 65 + j0 + 3] = v.w * v.w;
    }
    if (t < 64) mld[t] = means[(size_t)t * O_N + o];
    __syncthreads();
    if (t < 64) {
        float u = 0.f;
#pragma unroll
        for (int i = 0; i < 64; ++i) u = fmaf(s[i * 65 + t], mld[i], u);
        uw[t] = u;
    } else if (t < 128) {
        const int j = t - 64;
        float w = 0.f;
#pragma unroll
        for (int i = 0; i < 64; ++i) w = fmaf(s[j * 65 + i], mld[i], w);
        uw[64 + j] = w;
    }
    __syncthreads();
    if (t < 64) {
        const float c = -(uw[t] + uw[64 + t]);
        const __bf16 hi = (__bf16)c;
        const __bf16 lo = (__bf16)(c - (float)hi);
        const size_t eidx = (size_t)(o >> 5) * 2048 + (size_t)(t >> 4) * 512
                          + (size_t)(o & 31) * 16 + (t & 15);
        cPhi[eidx] = hi;
        cPlo[eidx] = lo;
    }
    if (t == 0) {
        float kk = 0.f;
#pragma unroll
        for (int j = 0; j < 64; ++j) kk = fmaf(uw[j], mld[j], kk);
        kArr[o] = kk;
    }
#pragma unroll
    for (int r = 0; r < 2; ++r) {
        const int ch = r * 256 + t;
        const int ss = ch >> 7;
        const int j = (ch >> 1) & 63;
        const int hh = ch & 1;
        bf16x8 v;
#pragma unroll
        for (int e = 0; e < 8; ++e)
            v[e] = (__bf16)s[(16 * ss + 8 * hh + e) * 65 + j];
        *(bf16x8*)(Atp + (size_t)o * 4096 + (size_t)ch * 8) = v;
    }
}

// ---------------------------------------------------------------------------
// main: block = 128 rows x 32 o's; 4 waves x 32 rows; grid 1024, 4 blocks/CU.
// 2-o phases: one barrier per 2 panels (16 MFMA between barriers), 4 LDS
// buffers, stage phase p+1 during phase p. lin(+k) lives in registers
// (owner-half indexed, fully unrolled via macros). Dot uses packed f32 fma.
// C-layout (32x32): col = lane&31, row = (reg&3)+8*(reg>>2)+4*(lane>>5);
// owner half of o=i is h = (i>>2)&1, register r(i) = (i&3) + ((i>>3)<<2).
// ---------------------------------------------------------------------------
__global__ __launch_bounds__(256, 4) void rbf_main(
    const float* __restrict__ x, const __bf16* __restrict__ Atp,
    const __bf16* __restrict__ cPhi, const __bf16* __restrict__ cPlo,
    const float* __restrict__ kArr, float* __restrict__ out)
{
    __shared__ __align__(16) __bf16 sA[4][4096];

    const int tid = threadIdx.x;
    const int wave = tid >> 6;
    const int lane = tid & 63;
    const int b = lane & 31;
    const int h = lane >> 5;

    // 1024 blocks = 8 XCD x (8 og x 16 bg); per-XCD Atp slice = 2MB in its L2
    const int wg = (int)blockIdx.x;
    const int xcd = wg & 7;
    const int loc = wg >> 3;
    const int og = xcd * 8 + (loc >> 4);
    const int bg = loc & 15;
    const int oBase = og * 32;
    const int rowW = bg * 128 + wave * 32;

    const float* xr = x + (size_t)(rowW + b) * K_N;

    const f32x16 zz = {0.f,0.f,0.f,0.f,0.f,0.f,0.f,0.f,
                       0.f,0.f,0.f,0.f,0.f,0.f,0.f,0.f};

    // x bf16 B-op frags + f32 dot copies; lin(+k) computed into registers
    bf16x8 xh[4];
    f32x4 xd[2][4];
    f32x16 lin;
    {
        bf16x8 xl[4];
#pragma unroll
        for (int ss = 0; ss < 4; ++ss) {
            const float* p = xr + ss * 16 + h * 8;
            bf16x8 vh, vl;
#pragma unroll
            for (int e = 0; e < 8; ++e) {
                const float v = p[e];
                const __bf16 hi = (__bf16)v;
                vh[e] = hi;
                vl[e] = (__bf16)(v - (float)hi);
            }
            xh[ss] = vh; xl[ss] = vl;
        }
#pragma unroll
        for (int mt = 0; mt < 2; ++mt)
#pragma unroll
            for (int rq = 0; rq < 4; ++rq)
                xd[mt][rq] = *(const f32x4*)(xr + mt * 32 + rq * 8 + h * 4);

        const __bf16* chp = cPhi + (size_t)og * 2048;
        const __bf16* clp = cPlo + (size_t)og * 2048;
        lin = zz;
#pragma unroll
        for (int ss = 0; ss < 4; ++ss) {
            const bf16x8 fh = *(const bf16x8*)(chp + ss * 512 + b * 16 + h * 8);
            const bf16x8 fl = *(const bf16x8*)(clp + ss * 512 + b * 16 + h * 8);
            lin = __builtin_amdgcn_mfma_f32_32x32x16_bf16(fh, xh[ss], lin, 0, 0, 0);
            lin = __builtin_amdgcn_mfma_f32_32x32x16_bf16(fh, xl[ss], lin, 0, 0, 0);
            lin = __builtin_amdgcn_mfma_f32_32x32x16_bf16(fl, xh[ss], lin, 0, 0, 0);
        }
#pragma unroll
        for (int r = 0; r < 16; ++r)
            lin[r] += kArr[oBase + (r & 3) + 8 * (r >> 2) + 4 * h];
    }

    // staging: linear LDS dest, pre-swizzled global src (involution swz)
    const int L0 = tid * 16, L1 = 4096 + tid * 16;
    const int S0 = L0 ^ (((L0 >> 7) & 7) << 4);
    const int S1 = L1 ^ (((L1 >> 7) & 7) << 4);
    const char* gp = (const char*)(Atp + (size_t)oBase * 4096);
    gld16(gp + S0, (char*)&sA[0][0] + L0);           // panel 0
    gld16(gp + S1, (char*)&sA[0][0] + L1);
    gld16(gp + 8192 + S0, (char*)&sA[1][0] + L0);    // panel 1
    gld16(gp + 8192 + S1, (char*)&sA[1][0] + L1);

    const int off0 = (b * 32 + h * 16) ^ (((b >> 2) & 7) << 4);
    float* outp = out + (size_t)(rowW + b) * O_N + oBase;
    float q4[4];

#define RBF_COMPUTE(I) do {                                                   \
    const char* bufp_ = (const char*)&sA[(I) & 3][0];                         \
    __builtin_amdgcn_s_setprio(1);                                            \
    f32x16 a0_, a1_;                                                          \
    {                                                                         \
        const bf16x8 f0_ = *(const bf16x8*)(bufp_ + off0);                    \
        const bf16x8 f1_ = *(const bf16x8*)(bufp_ + 1024 + off0);             \
        a0_ = __builtin_amdgcn_mfma_f32_32x32x16_bf16(f0_, xh[0], zz, 0, 0, 0); \
        a1_ = __builtin_amdgcn_mfma_f32_32x32x16_bf16(f1_, xh[0], zz, 0, 0, 0); \
    }                                                                         \
    _Pragma("unroll")                                                         \
    for (int ss = 1; ss < 4; ++ss) {                                          \
        const char* base_ = bufp_ + ss * 2048;                                \
        const bf16x8 f0_ = *(const bf16x8*)(base_ + off0);                    \
        const bf16x8 f1_ = *(const bf16x8*)(base_ + 1024 + off0);             \
        a0_ = __builtin_amdgcn_mfma_f32_32x32x16_bf16(f0_, xh[ss], a0_, 0, 0, 0); \
        a1_ = __builtin_amdgcn_mfma_f32_32x32x16_bf16(f1_, xh[ss], a1_, 0, 0, 0); \
    }                                                                         \
    __builtin_amdgcn_s_setprio(0);                                            \
    f32x2 P0_ = {0.f, 0.f}, P1_ = {0.f, 0.f};                                 \
    _Pragma("unroll")                                                         \
    for (int rg = 0; rg < 4; ++rg) {                                          \
        f32x2 u_, v_;                                                         \
        u_[0] = a0_[rg*4+0]; u_[1] = a0_[rg*4+1];                             \
        v_[0] = xd[0][rg][0]; v_[1] = xd[0][rg][1];                           \
        P0_ = __builtin_elementwise_fma(u_, v_, P0_);                         \
        u_[0] = a0_[rg*4+2]; u_[1] = a0_[rg*4+3];                             \
        v_[0] = xd[0][rg][2]; v_[1] = xd[0][rg][3];                           \
        P1_ = __builtin_elementwise_fma(u_, v_, P1_);                         \
        u_[0] = a1_[rg*4+0]; u_[1] = a1_[rg*4+1];                             \
        v_[0] = xd[1][rg][0]; v_[1] = xd[1][rg][1];                           \
        P0_ = __builtin_elementwise_fma(u_, v_, P0_);                         \
        u_[0] = a1_[rg*4+2]; u_[1] = a1_[rg*4+3];                             \
        v_[0] = xd[1][rg][2]; v_[1] = xd[1][rg][3];                           \
        P1_ = __builtin_elementwise_fma(u_, v_, P1_);                         \
    }                                                                         \
    const f32x2 Ps_ = P0_ + P1_;                                              \
    float q_ = Ps_[0] + Ps_[1];                                               \
    q_ += __shfl_xor(q_, 32, 64);                                             \
    if (h == (((I) >> 2) & 1)) {                                              \
        q4[(I) & 3] = exp2f((q_ + lin[((I) & 3) + (((I) >> 3) << 2)])         \
                            * -0.72134752044448170368f);                      \
        if (((I) & 3) == 3) {                                                 \
            const f32x4 v_ = {q4[0], q4[1], q4[2], q4[3]};                    \
            *(f32x4*)(outp + ((I) - 3)) = v_;                                 \
        }                                                                     \
    }                                                                         \
} while (0)

#define RBF_PHASE(P) do {                                                     \
    __syncthreads();                                                          \
    if ((P) < 15) {                                                           \
        const char* g2_ = gp + (size_t)(2 * (P) + 2) * 8192;                  \
        char* d2_ = (char*)&sA[(2 * (P) + 2) & 3][0];                         \
        gld16(g2_ + S0, d2_ + L0);                                            \
        gld16(g2_ + S1, d2_ + L1);                                            \
        const char* g3_ = gp + (size_t)(2 * (P) + 3) * 8192;                  \
        char* d3_ = (char*)&sA[(2 * (P) + 3) & 3][0];                         \
        gld16(g3_ + S0, d3_ + L0);                                            \
        gld16(g3_ + S1, d3_ + L1);                                            \
    }                                                                         \
    RBF_COMPUTE(2 * (P));                                                     \
    RBF_COMPUTE(2 * (P) + 1);                                                 \
} while (0)

    RBF_PHASE(0);  RBF_PHASE(1);  RBF_PHASE(2);  RBF_PHASE(3);
    RBF_PHASE(4);  RBF_PHASE(5);  RBF_PHASE(6);  RBF_PHASE(7);
    RBF_PHASE(8);  RBF_PHASE(9);  RBF_PHASE(10); RBF_PHASE(11);
    RBF_PHASE(12); RBF_PHASE(13); RBF_PHASE(14); RBF_PHASE(15);

#undef RBF_PHASE
#undef RBF_COMPUTE
}

extern "C" void kernel_launch(void* const* d_in, const int* in_sizes, int n_in,
                              void* d_out, int out_size, void* d_ws, size_t ws_size,
                              hipStream_t stream)
{
    const float* x = (const float*)d_in[0];
    const float* means = (const float*)d_in[1];
    const float* inv = (const float*)d_in[2];
    float* out = (float*)d_out;

    char* w = (char*)d_ws;
    __bf16* Atp  = (__bf16*)w;                                     // 16.78 MB
    __bf16* cPhi = (__bf16*)(w + (size_t)O_N * 4096 * 2);          // 256 KB
    __bf16* cPlo = (__bf16*)(w + (size_t)O_N * 4096 * 2 + 262144); // 256 KB
    float*  kArr = (float*)(w + (size_t)O_N * 4096 * 2 + 524288);  // 8 KB

    rbf_prep<<<dim3(O_N), dim3(256), 0, stream>>>(inv, means, Atp, cPhi, cPlo, kArr);
    rbf_main<<<dim3(1024), dim3(256), 0, stream>>>(x, Atp, cPhi, cPlo, kArr, out);

    (void)in_sizes; (void)n_in; (void)out_size; (void)ws_size;
}